// Round 8
// baseline (358.804 us; speedup 1.0000x reference)
//
#include <hip/hip_runtime.h>
#include <math.h>

#define N_S   1024
#define N_T   1024
#define E_EDG 16384
#define R     32
#define NSTEP 2

// ---------------------------------------------------------------------------
// k_pre: G = W1 W1^T + W2 W2^T (blocks 0..127) ; zero rt0,rt1,aggs0,aggs1
// (blocks 128..255; contiguous 131072 floats). grid 256 x 256
// ---------------------------------------------------------------------------
__global__ __launch_bounds__(256) void k_pre(const float* __restrict__ W1,
                                             const float* __restrict__ W2,
                                             float* __restrict__ G,
                                             float* __restrict__ zbuf) {
    const int t = threadIdx.x, bid = blockIdx.x;
    if (bid >= 128) {
        ((float4*)zbuf)[(bid - 128) * 256 + t] = make_float4(0.f, 0.f, 0.f, 0.f);
        return;
    }
    __shared__ float wa[512];
    __shared__ float wt[64][129];
    __shared__ float red[256];
    const int a = bid;
    for (int s = t; s < 512; s += 256)
        wa[s] = (s < 256) ? W1[a * 256 + s] : W2[a * 256 + (s - 256)];
    __syncthreads();
    float acc = 0.f;
    const int b = t & 127, h = t >> 7;
    for (int ci = 0; ci < 8; ++ci) {
        const float* Wsrc = (ci < 4) ? W1 : W2;
        const int cbase = (ci & 3) * 64;
#pragma unroll
        for (int it = 0; it < 8; ++it) {
            int s = it * 256 + t;
            int br = s >> 4, q = s & 15;
            float4 v = *(const float4*)(Wsrc + (size_t)br * 256 + cbase + q * 4);
            wt[q * 4 + 0][br] = v.x; wt[q * 4 + 1][br] = v.y;
            wt[q * 4 + 2][br] = v.z; wt[q * 4 + 3][br] = v.w;
        }
        __syncthreads();
        const float* wac = wa + ci * 64 + h * 32;
#pragma unroll
        for (int cc = 0; cc < 32; ++cc)
            acc += wac[cc] * wt[h * 32 + cc][b];
        __syncthreads();
    }
    red[t] = acc;
    __syncthreads();
    if (t < 128) G[a * 128 + t] = red[t] + red[t + 128];
}

// ---------------------------------------------------------------------------
// k_build: s-graph scatter (both steps) + per-tile Ys = X[idx1]@G (redundant
// x16) + Shat 64x64 tile + softmax partials. grid 256 x 256. LDS ~66KB.
// ---------------------------------------------------------------------------
__global__ __launch_bounds__(256) void k_build(
    const float* __restrict__ X, const int* __restrict__ idx1,
    const int* __restrict__ idx2, const int* __restrict__ es,
    const float* __restrict__ rs_all, const float* __restrict__ G,
    float* aggs0, float* aggs1,
    float* __restrict__ Shat, float2* __restrict__ part) {
    __shared__ float As[64][132];
    union U { float Xs[64][128]; float Bs[64][132]; };
    __shared__ U u;
    const int t = threadIdx.x, bid = blockIdx.x;
    const int i0 = (bid >> 4) * 64, j0 = (bid & 15) * 64, jt = bid & 15;

    // s-graph scatter slice (both steps), grid-strided
    for (int v = bid * 256 + t; v < 2 * E_EDG * 32; v += 65536) {
        int k = v & 31, ei = v >> 5;
        int step = ei >> 14, e = ei & (E_EDG - 1);
        int src = es[e], dst = es[E_EDG + e];
        const float* rs = rs_all + (size_t)step * N_S * R;
        float* aggs = step ? aggs1 : aggs0;
        atomicAdd(&aggs[(size_t)dst * 32 + k], rs[(size_t)src * 32 + k]);
    }

    // stage A-side raw rows X[idx1]
    for (int s = t; s < 64 * 32; s += 256) {
        int row = s >> 5, q = s & 31;
        *(float4*)&u.Xs[row][q * 4] =
            ((const float4*)(X + (size_t)idx1[i0 + row] * 128))[q];
    }
    __syncthreads();

    // Ys: As[row][a] = sum_d Xs[row][d] * G[d*128+a]
    {
        const int a = t & 127, h = t >> 7;
        float acc[32];
#pragma unroll
        for (int r = 0; r < 32; ++r) acc[r] = 0.f;
        for (int dq = 0; dq < 32; ++dq) {
            const float* gp = G + dq * 4 * 128 + a;
            float g0 = gp[0], g1 = gp[128], g2 = gp[256], g3 = gp[384];
#pragma unroll
            for (int r = 0; r < 32; ++r) {
                float4 x = *(const float4*)&u.Xs[h * 32 + r][dq * 4];
                acc[r] += x.x * g0 + x.y * g1 + x.z * g2 + x.w * g3;
            }
        }
#pragma unroll
        for (int r = 0; r < 32; ++r) As[h * 32 + r][a] = acc[r];
    }
    __syncthreads();

    // stage B-side raw rows X[idx2] (overwrites Xs region)
    for (int s = t; s < 64 * 32; s += 256) {
        int row = s >> 5, q = s & 31;
        *(float4*)&u.Bs[row][q * 4] =
            ((const float4*)(X + (size_t)idx2[j0 + row] * 128))[q];
    }
    __syncthreads();

    // Shat tile + partials (verified R1 core)
    const int r = t >> 4, c = t & 15;
    float acc[4][4] = {};
    for (int k = 0; k < 128; k += 4) {
        float4 ya[4], xb[4];
#pragma unroll
        for (int a2 = 0; a2 < 4; ++a2) ya[a2] = *(const float4*)&As[r + 16 * a2][k];
#pragma unroll
        for (int b2 = 0; b2 < 4; ++b2) xb[b2] = *(const float4*)&u.Bs[c + 16 * b2][k];
#pragma unroll
        for (int a2 = 0; a2 < 4; ++a2)
#pragma unroll
            for (int b2 = 0; b2 < 4; ++b2)
                acc[a2][b2] += ya[a2].x * xb[b2].x + ya[a2].y * xb[b2].y +
                               ya[a2].z * xb[b2].z + ya[a2].w * xb[b2].w;
    }
#pragma unroll
    for (int a2 = 0; a2 < 4; ++a2) {
#pragma unroll
        for (int b2 = 0; b2 < 4; ++b2)
            Shat[(size_t)(i0 + r + 16 * a2) * 1024 + (j0 + c + 16 * b2)] = acc[a2][b2];
        float M = fmaxf(fmaxf(acc[a2][0], acc[a2][1]), fmaxf(acc[a2][2], acc[a2][3]));
#pragma unroll
        for (int m = 1; m < 16; m <<= 1) M = fmaxf(M, __shfl_xor(M, m, 16));
        float Ss = 0.f;
#pragma unroll
        for (int b2 = 0; b2 < 4; ++b2) Ss += __expf(acc[a2][b2] - M);
#pragma unroll
        for (int m = 1; m < 16; m <<= 1) Ss += __shfl_xor(Ss, m, 16);
        if (c == 0)
            part[(size_t)(i0 + r + 16 * a2) * 16 + jt] = make_float2(M, Ss);
    }
}

// ---------------------------------------------------------------------------
// k_rt: rt[j,k] += sum_i softmax(Shat)[i,j]*rs[i,k]; inline softmax from
// partials; step0 writes S_0 to out0. grid (16 jt, 8 ichunk) x 256. (R1)
// ---------------------------------------------------------------------------
__global__ __launch_bounds__(256) void k_rt(const float* __restrict__ Shat,
                                            const float2* __restrict__ part,
                                            const float* __restrict__ rs,
                                            float* __restrict__ rt,
                                            float* __restrict__ out0) {
    int j0 = blockIdx.x * 64;
    int i0 = blockIdx.y * 128;
    int t = threadIdx.x;
    __shared__ float Sl[16][68];
    __shared__ float Rl[16][36];
    __shared__ float mrow[128], irow[128];
    if (t < 128) {
        const float2* pr = part + (size_t)(i0 + t) * 16;
        float M = -1e30f, S = 0.f;
        float2 ps[16];
#pragma unroll
        for (int q = 0; q < 16; ++q) { ps[q] = pr[q]; M = fmaxf(M, ps[q].x); }
#pragma unroll
        for (int q = 0; q < 16; ++q) S += ps[q].y * __expf(ps[q].x - M);
        mrow[t] = M;
        irow[t] = 1.f / S;
    }
    __syncthreads();
    int k = t & 31, jg = t >> 5;
    float acc[8] = {};
    for (int ic = 0; ic < 128; ic += 16) {
        for (int s = t; s < 16 * 16; s += 256) {
            int row = s >> 4, q = s & 15;
            int lr = ic + row;
            float4 v = ((const float4*)(Shat + (size_t)(i0 + lr) * 1024 + j0))[q];
            float m = mrow[lr], inv = irow[lr];
            v.x = __expf(v.x - m) * inv;
            v.y = __expf(v.y - m) * inv;
            v.z = __expf(v.z - m) * inv;
            v.w = __expf(v.w - m) * inv;
            *(float4*)&Sl[row][q * 4] = v;
            if (out0)
                ((float4*)(out0 + (size_t)(i0 + lr) * 1024 + j0))[q] = v;
        }
        for (int s = t; s < 16 * 8; s += 256) {
            int row = s >> 3, q = s & 7;
            *(float4*)&Rl[row][q * 4] =
                ((const float4*)(rs + (size_t)(i0 + ic + row) * 32))[q];
        }
        __syncthreads();
#pragma unroll
        for (int ii = 0; ii < 16; ++ii) {
            float rv = Rl[ii][k];
#pragma unroll
            for (int m = 0; m < 8; ++m)
                acc[m] += Sl[ii][jg * 8 + m] * rv;
        }
        __syncthreads();
    }
#pragma unroll
    for (int m = 0; m < 8; ++m)
        atomicAdd(&rt[(size_t)(j0 + jg * 8 + m) * 32 + k], acc[m]);
}

// ---------------------------------------------------------------------------
// k_delta: per 64x64 tile — gather aggt in LDS from the t-edge list, compute
// P (rows i0..) and Q (rows j0..) redundantly via wave-32 shfl matmuls, then
// Shat += bm2 + Wm2 . relu(P-Q), emit new softmax partials. grid (16,16)x256.
// ---------------------------------------------------------------------------
__global__ __launch_bounds__(256) void k_delta(
    const float* __restrict__ rs, const float* __restrict__ aggs,
    const float* __restrict__ rt, const int* __restrict__ et,
    const float* __restrict__ W3, const float* __restrict__ b3,
    const float* __restrict__ Wm1, const float* __restrict__ bm1,
    const float* __restrict__ Wm2, const float* __restrict__ bm2,
    float* __restrict__ Shat, float2* __restrict__ part) {
    __shared__ float w3[1024], wm1[1024];
    __shared__ float us[64][33], rq[64][33], agg[64][33];
    __shared__ float Pl[64][36], Ql[64][36];
    __shared__ ushort2 elist[2048];
    __shared__ int ecnt;
    const int t = threadIdx.x;
    const int bx = blockIdx.x, by = blockIdx.y;
    const int i0 = by * 64, j0 = bx * 64;

    for (int s = t; s < 1024; s += 256) { w3[s] = W3[s]; wm1[s] = Wm1[s]; }
    if (t == 0) ecnt = 0;
    for (int s = t; s < 64 * 8; s += 256) {
        int row = s >> 3, q = s & 7;
        float4 a4 = ((const float4*)(rs + (size_t)(i0 + row) * 32))[q];
        float4 b4 = ((const float4*)(aggs + (size_t)(i0 + row) * 32))[q];
        a4.x += b4.x; a4.y += b4.y; a4.z += b4.z; a4.w += b4.w;
        *(float4*)&us[row][q * 4] = a4;
        *(float4*)&rq[row][q * 4] = ((const float4*)(rt + (size_t)(j0 + row) * 32))[q];
        *(float4*)&agg[row][q * 4] = make_float4(0.f, 0.f, 0.f, 0.f);
    }
    __syncthreads();

    // filter t-graph edges whose dst falls in this j-tile
    for (int e = t; e < E_EDG; e += 256) {
        int dst = et[E_EDG + e];
        if ((dst >> 6) == bx) {
            int p = atomicAdd(&ecnt, 1);
            if (p < 2048)
                elist[p] = make_ushort2((unsigned short)et[e],
                                        (unsigned short)(dst & 63));
        }
    }
    __syncthreads();

    const int k = t & 31, team = t >> 5;
    const int ne = (ecnt < 2048) ? ecnt : 2048;
    for (int idx = team; idx < ne; idx += 8) {
        ushort2 ed = elist[idx];
        atomicAdd(&agg[ed.y][k], rt[(size_t)ed.x * 32 + k]);
    }
    __syncthreads();

    // P and Q: 8 rows per pass (team = row within pass), wave-32 shfl matmul
    const float b3k = b3[k], bm1k = bm1[k];
    for (int p = 0; p < 8; ++p) {
        const int row = p * 8 + team;
        float acc = b3k;
#pragma unroll
        for (int m = 0; m < 32; ++m) acc += us[row][m] * w3[m * 32 + k];
        float o = fmaxf(acc, 0.f);
        float pv = bm1k;
#pragma unroll
        for (int m = 0; m < 32; ++m) pv += __shfl(o, m, 32) * wm1[m * 32 + k];
        Pl[row][k] = pv;
        float acc2 = b3k;
#pragma unroll
        for (int m = 0; m < 32; ++m) acc2 += (rq[row][m] + agg[row][m]) * w3[m * 32 + k];
        float o2 = fmaxf(acc2, 0.f);
        float qv = 0.f;
#pragma unroll
        for (int m = 0; m < 32; ++m) qv += __shfl(o2, m, 32) * wm1[m * 32 + k];
        Ql[row][k] = qv;
    }
    __syncthreads();

    // delta core + Shat update + new partials (verified R1 core)
    const int r = t >> 4, c = t & 15;
    const float bv = bm2[0];
    float acc[4][4] = {};
#pragma unroll
    for (int q = 0; q < 8; ++q) {
        float4 w = ((const float4*)Wm2)[q];
        float4 pa[4], qb[4];
#pragma unroll
        for (int a = 0; a < 4; ++a) pa[a] = *(const float4*)&Pl[r + 16 * a][q * 4];
#pragma unroll
        for (int b = 0; b < 4; ++b) qb[b] = *(const float4*)&Ql[c + 16 * b][q * 4];
#pragma unroll
        for (int a = 0; a < 4; ++a)
#pragma unroll
            for (int b = 0; b < 4; ++b)
                acc[a][b] += w.x * fmaxf(pa[a].x - qb[b].x, 0.f)
                           + w.y * fmaxf(pa[a].y - qb[b].y, 0.f)
                           + w.z * fmaxf(pa[a].z - qb[b].z, 0.f)
                           + w.w * fmaxf(pa[a].w - qb[b].w, 0.f);
    }
#pragma unroll
    for (int a = 0; a < 4; ++a) {
        float v[4];
#pragma unroll
        for (int b = 0; b < 4; ++b) {
            size_t idx = (size_t)(i0 + r + 16 * a) * 1024 + (j0 + c + 16 * b);
            v[b] = Shat[idx] + acc[a][b] + bv;
            Shat[idx] = v[b];
        }
        float M = fmaxf(fmaxf(v[0], v[1]), fmaxf(v[2], v[3]));
#pragma unroll
        for (int m = 1; m < 16; m <<= 1) M = fmaxf(M, __shfl_xor(M, m, 16));
        float Ss = 0.f;
#pragma unroll
        for (int b = 0; b < 4; ++b) Ss += __expf(v[b] - M);
#pragma unroll
        for (int m = 1; m < 16; m <<= 1) Ss += __shfl_xor(Ss, m, 16);
        if (c == 0)
            part[(size_t)(i0 + r + 16 * a) * 16 + bx] = make_float2(M, Ss);
    }
}

// ---------------------------------------------------------------------------
// k_fsm: final softmax S_L from partials. grid 1024 x 256. (R1)
// ---------------------------------------------------------------------------
__global__ __launch_bounds__(256) void k_fsm(const float* __restrict__ Shat,
                                             const float2* __restrict__ part,
                                             float* __restrict__ out2) {
    int i = blockIdx.x, t = threadIdx.x;
    const float2* pr = part + (size_t)i * 16;
    float M = -1e30f, S = 0.f;
    float2 ps[16];
#pragma unroll
    for (int q = 0; q < 16; ++q) { ps[q] = pr[q]; M = fmaxf(M, ps[q].x); }
#pragma unroll
    for (int q = 0; q < 16; ++q) S += ps[q].y * __expf(ps[q].x - M);
    float inv = 1.f / S;
    const float* row = Shat + (size_t)i * 1024;
#pragma unroll
    for (int j = 0; j < 4; ++j)
        out2[(size_t)i * 1024 + t + 256 * j] = __expf(row[t + 256 * j] - M) * inv;
}

// ---------------------------------------------------------------------------
extern "C" void kernel_launch(void* const* d_in, const int* in_sizes, int n_in,
                              void* d_out, int out_size, void* d_ws, size_t ws_size,
                              hipStream_t stream) {
    const float* inputs = (const float*)d_in[0];
    const int*   idx1   = (const int*)d_in[1];
    const int*   idx2   = (const int*)d_in[2];
    const int*   es     = (const int*)d_in[3];
    const int*   et     = (const int*)d_in[4];
    const float* W1     = (const float*)d_in[5];
    const float* W2     = (const float*)d_in[6];
    const float* W3     = (const float*)d_in[7];
    const float* b3     = (const float*)d_in[8];
    const float* Wm1    = (const float*)d_in[9];
    const float* bm1    = (const float*)d_in[10];
    const float* Wm2    = (const float*)d_in[11];
    const float* bm2    = (const float*)d_in[12];
    const float* rs_all = (const float*)d_in[13];
    float* out = (float*)d_out;
    float* ws  = (float*)d_ws;

    // workspace layout (floats)
    float*  Shat  = ws;                       // 1,048,576
    float*  G     = Shat + (1 << 20);         // 16,384
    float2* part  = (float2*)(G + 16384);     // 32,768 floats
    float*  rt0   = G + 16384 + 32768;        // 32,768 ┐ contiguous zero range
    float*  rt1   = rt0 + 32768;              // 32,768 │ (rt0..aggs1, 131072)
    float*  aggs0 = rt1 + 32768;              // 32,768 │
    float*  aggs1 = aggs0 + 32768;            // 32,768 ┘

    k_pre<<<256, 256, 0, stream>>>(W1, W2, G, rt0);
    k_build<<<256, 256, 0, stream>>>(inputs, idx1, idx2, es, rs_all, G,
                                     aggs0, aggs1, Shat, part);
    for (int step = 0; step < NSTEP; ++step) {
        const float* rs   = rs_all + (size_t)step * N_S * R;
        float*       rtS  = step ? rt1 : rt0;
        const float* aggS = step ? aggs1 : aggs0;
        k_rt<<<dim3(16, 8), 256, 0, stream>>>(Shat, part, rs, rtS,
                                              step == 0 ? out : nullptr);
        k_delta<<<dim3(16, 16), 256, 0, stream>>>(rs, aggS, rtS, et,
                                                  W3, b3, Wm1, bm1, Wm2, bm2,
                                                  Shat, part);
    }
    k_fsm<<<1024, 256, 0, stream>>>(Shat, part, out + (1 << 20));
}

// Round 9
// 211.927 us; speedup vs baseline: 1.6931x; 1.6931x over previous
//
#include <hip/hip_runtime.h>
#include <math.h>

#define N_S   1024
#define N_T   1024
#define E_EDG 16384
#define R     32
#define NSTEP 2

// ---------------------------------------------------------------------------
// k_pre: G = W1 W1^T + W2 W2^T (blocks 0..127) ; zero rt0,rt1,aggs0,aggs1,
// aggt0,aggt1 (blocks 128..319; contiguous 196608 floats). grid 320 x 256
// ---------------------------------------------------------------------------
__global__ __launch_bounds__(256) void k_pre(const float* __restrict__ W1,
                                             const float* __restrict__ W2,
                                             float* __restrict__ G,
                                             float* __restrict__ zbuf) {
    const int t = threadIdx.x, bid = blockIdx.x;
    if (bid >= 128) {
        ((float4*)zbuf)[(bid - 128) * 256 + t] = make_float4(0.f, 0.f, 0.f, 0.f);
        return;
    }
    __shared__ float wa[512];
    __shared__ float wt[64][129];
    __shared__ float red[256];
    const int a = bid;
    for (int s = t; s < 512; s += 256)
        wa[s] = (s < 256) ? W1[a * 256 + s] : W2[a * 256 + (s - 256)];
    __syncthreads();
    float acc = 0.f;
    const int b = t & 127, h = t >> 7;
    for (int ci = 0; ci < 8; ++ci) {
        const float* Wsrc = (ci < 4) ? W1 : W2;
        const int cbase = (ci & 3) * 64;
#pragma unroll
        for (int it = 0; it < 8; ++it) {
            int s = it * 256 + t;
            int br = s >> 4, q = s & 15;
            float4 v = *(const float4*)(Wsrc + (size_t)br * 256 + cbase + q * 4);
            wt[q * 4 + 0][br] = v.x; wt[q * 4 + 1][br] = v.y;
            wt[q * 4 + 2][br] = v.z; wt[q * 4 + 3][br] = v.w;
        }
        __syncthreads();
        const float* wac = wa + ci * 64 + h * 32;
#pragma unroll
        for (int cc = 0; cc < 32; ++cc)
            acc += wac[cc] * wt[h * 32 + cc][b];
        __syncthreads();
    }
    red[t] = acc;
    __syncthreads();
    if (t < 128) G[a * 128 + t] = red[t] + red[t + 128];
}

// ---------------------------------------------------------------------------
// k_build: s-graph scatter (both steps) + per-tile Ys = X[idx1]@G (redundant
// x16) + Shat 64x64 tile + softmax partials. grid 256 x 256. (R8-verified)
// ---------------------------------------------------------------------------
__global__ __launch_bounds__(256) void k_build(
    const float* __restrict__ X, const int* __restrict__ idx1,
    const int* __restrict__ idx2, const int* __restrict__ es,
    const float* __restrict__ rs_all, const float* __restrict__ G,
    float* aggs0, float* aggs1,
    float* __restrict__ Shat, float2* __restrict__ part) {
    __shared__ float As[64][132];
    union U { float Xs[64][128]; float Bs[64][132]; };
    __shared__ U u;
    const int t = threadIdx.x, bid = blockIdx.x;
    const int i0 = (bid >> 4) * 64, j0 = (bid & 15) * 64, jt = bid & 15;

    for (int v = bid * 256 + t; v < 2 * E_EDG * 32; v += 65536) {
        int k = v & 31, ei = v >> 5;
        int step = ei >> 14, e = ei & (E_EDG - 1);
        int src = es[e], dst = es[E_EDG + e];
        const float* rs = rs_all + (size_t)step * N_S * R;
        float* aggs = step ? aggs1 : aggs0;
        atomicAdd(&aggs[(size_t)dst * 32 + k], rs[(size_t)src * 32 + k]);
    }

    for (int s = t; s < 64 * 32; s += 256) {
        int row = s >> 5, q = s & 31;
        *(float4*)&u.Xs[row][q * 4] =
            ((const float4*)(X + (size_t)idx1[i0 + row] * 128))[q];
    }
    __syncthreads();

    {
        const int a = t & 127, h = t >> 7;
        float acc[32];
#pragma unroll
        for (int r = 0; r < 32; ++r) acc[r] = 0.f;
        for (int dq = 0; dq < 32; ++dq) {
            const float* gp = G + dq * 4 * 128 + a;
            float g0 = gp[0], g1 = gp[128], g2 = gp[256], g3 = gp[384];
#pragma unroll
            for (int r = 0; r < 32; ++r) {
                float4 x = *(const float4*)&u.Xs[h * 32 + r][dq * 4];
                acc[r] += x.x * g0 + x.y * g1 + x.z * g2 + x.w * g3;
            }
        }
#pragma unroll
        for (int r = 0; r < 32; ++r) As[h * 32 + r][a] = acc[r];
    }
    __syncthreads();

    for (int s = t; s < 64 * 32; s += 256) {
        int row = s >> 5, q = s & 31;
        *(float4*)&u.Bs[row][q * 4] =
            ((const float4*)(X + (size_t)idx2[j0 + row] * 128))[q];
    }
    __syncthreads();

    const int r = t >> 4, c = t & 15;
    float acc[4][4] = {};
    for (int k = 0; k < 128; k += 4) {
        float4 ya[4], xb[4];
#pragma unroll
        for (int a2 = 0; a2 < 4; ++a2) ya[a2] = *(const float4*)&As[r + 16 * a2][k];
#pragma unroll
        for (int b2 = 0; b2 < 4; ++b2) xb[b2] = *(const float4*)&u.Bs[c + 16 * b2][k];
#pragma unroll
        for (int a2 = 0; a2 < 4; ++a2)
#pragma unroll
            for (int b2 = 0; b2 < 4; ++b2)
                acc[a2][b2] += ya[a2].x * xb[b2].x + ya[a2].y * xb[b2].y +
                               ya[a2].z * xb[b2].z + ya[a2].w * xb[b2].w;
    }
#pragma unroll
    for (int a2 = 0; a2 < 4; ++a2) {
#pragma unroll
        for (int b2 = 0; b2 < 4; ++b2)
            Shat[(size_t)(i0 + r + 16 * a2) * 1024 + (j0 + c + 16 * b2)] = acc[a2][b2];
        float M = fmaxf(fmaxf(acc[a2][0], acc[a2][1]), fmaxf(acc[a2][2], acc[a2][3]));
#pragma unroll
        for (int m = 1; m < 16; m <<= 1) M = fmaxf(M, __shfl_xor(M, m, 16));
        float Ss = 0.f;
#pragma unroll
        for (int b2 = 0; b2 < 4; ++b2) Ss += __expf(acc[a2][b2] - M);
#pragma unroll
        for (int m = 1; m < 16; m <<= 1) Ss += __shfl_xor(Ss, m, 16);
        if (c == 0)
            part[(size_t)(i0 + r + 16 * a2) * 16 + jt] = make_float2(M, Ss);
    }
}

// ---------------------------------------------------------------------------
// k_rt: rt[j,k] += sum_i softmax(Shat)[i,j]*rs[i,k]; inline softmax from
// partials; step0 writes S_0 to out0. grid (16 jt, 8 ichunk) x 256. (verified)
// ---------------------------------------------------------------------------
__global__ __launch_bounds__(256) void k_rt(const float* __restrict__ Shat,
                                            const float2* __restrict__ part,
                                            const float* __restrict__ rs,
                                            float* __restrict__ rt,
                                            float* __restrict__ out0) {
    int j0 = blockIdx.x * 64;
    int i0 = blockIdx.y * 128;
    int t = threadIdx.x;
    __shared__ float Sl[16][68];
    __shared__ float Rl[16][36];
    __shared__ float mrow[128], irow[128];
    if (t < 128) {
        const float2* pr = part + (size_t)(i0 + t) * 16;
        float M = -1e30f, S = 0.f;
        float2 ps[16];
#pragma unroll
        for (int q = 0; q < 16; ++q) { ps[q] = pr[q]; M = fmaxf(M, ps[q].x); }
#pragma unroll
        for (int q = 0; q < 16; ++q) S += ps[q].y * __expf(ps[q].x - M);
        mrow[t] = M;
        irow[t] = 1.f / S;
    }
    __syncthreads();
    int k = t & 31, jg = t >> 5;
    float acc[8] = {};
    for (int ic = 0; ic < 128; ic += 16) {
        for (int s = t; s < 16 * 16; s += 256) {
            int row = s >> 4, q = s & 15;
            int lr = ic + row;
            float4 v = ((const float4*)(Shat + (size_t)(i0 + lr) * 1024 + j0))[q];
            float m = mrow[lr], inv = irow[lr];
            v.x = __expf(v.x - m) * inv;
            v.y = __expf(v.y - m) * inv;
            v.z = __expf(v.z - m) * inv;
            v.w = __expf(v.w - m) * inv;
            *(float4*)&Sl[row][q * 4] = v;
            if (out0)
                ((float4*)(out0 + (size_t)(i0 + lr) * 1024 + j0))[q] = v;
        }
        for (int s = t; s < 16 * 8; s += 256) {
            int row = s >> 3, q = s & 7;
            *(float4*)&Rl[row][q * 4] =
                ((const float4*)(rs + (size_t)(i0 + ic + row) * 32))[q];
        }
        __syncthreads();
#pragma unroll
        for (int ii = 0; ii < 16; ++ii) {
            float rv = Rl[ii][k];
#pragma unroll
            for (int m = 0; m < 8; ++m)
                acc[m] += Sl[ii][jg * 8 + m] * rv;
        }
        __syncthreads();
    }
#pragma unroll
    for (int m = 0; m < 8; ++m)
        atomicAdd(&rt[(size_t)(j0 + jg * 8 + m) * 32 + k], acc[m]);
}

// ---------------------------------------------------------------------------
// k_scat_t: aggt[dst] += rt[src].  grid 2048 x 256. (R1-verified)
// ---------------------------------------------------------------------------
__global__ __launch_bounds__(256) void k_scat_t(const int* __restrict__ et,
                                                const float* __restrict__ rt,
                                                float* __restrict__ aggt) {
    int gid = blockIdx.x * 256 + threadIdx.x;
    int k = gid & 31;
    int e = gid >> 5;
    int src = et[e], dst = et[E_EDG + e];
    atomicAdd(&aggt[(size_t)dst * 32 + k], rt[(size_t)src * 32 + k]);
}

// ---------------------------------------------------------------------------
// k_delta: per 64x64 tile — P rows (i-side) and Q rows (j-side) computed
// in-tile with REGISTER weight columns (w3r/wm1r, coalesced loads) + LDS
// broadcast operands (no shfl chains, no edge scan). Then
// Shat += bm2 + Wm2 . relu(P-Q), emit new softmax partials. grid (16,16)x256.
// ---------------------------------------------------------------------------
__global__ __launch_bounds__(256) void k_delta(
    const float* __restrict__ rs, const float* __restrict__ aggs,
    const float* __restrict__ rt, const float* __restrict__ aggt,
    const float* __restrict__ W3, const float* __restrict__ b3,
    const float* __restrict__ Wm1, const float* __restrict__ bm1,
    const float* __restrict__ Wm2, const float* __restrict__ bm2,
    float* __restrict__ Shat, float2* __restrict__ part) {
    __shared__ float us[64][33], uq[64][33];
    __shared__ float olP[64][33], olQ[64][33];
    __shared__ float Pl[64][36], Ql[64][36];
    const int t = threadIdx.x;
    const int bx = blockIdx.x, by = blockIdx.y;
    const int i0 = by * 64, j0 = bx * 64;
    const int k = t & 31, team = t >> 5;

    // weight columns into registers (coalesced: consecutive k per m-row)
    float w3r[32], wm1r[32];
#pragma unroll
    for (int m = 0; m < 32; ++m) {
        w3r[m]  = W3[m * 32 + k];
        wm1r[m] = Wm1[m * 32 + k];
    }
    const float b3k = b3[k], bm1k = bm1[k], bv = bm2[0];

    // stage us = rs+aggs (i-tile rows), uq = rt+aggt (j-tile rows)
    for (int s = t; s < 64 * 8; s += 256) {
        int row = s >> 3, q = s & 7;
        float4 a4 = ((const float4*)(rs + (size_t)(i0 + row) * 32))[q];
        float4 b4 = ((const float4*)(aggs + (size_t)(i0 + row) * 32))[q];
        a4.x += b4.x; a4.y += b4.y; a4.z += b4.z; a4.w += b4.w;
        *(float4*)&us[row][q * 4] = a4;
        float4 c4 = ((const float4*)(rt + (size_t)(j0 + row) * 32))[q];
        float4 d4 = ((const float4*)(aggt + (size_t)(j0 + row) * 32))[q];
        c4.x += d4.x; c4.y += d4.y; c4.z += d4.z; c4.w += d4.w;
        *(float4*)&uq[row][q * 4] = c4;
    }
    __syncthreads();

    // matmul1 + relu: o = relu(u @ W3 + b3), both sides, 8 rows/team-pass
#pragma unroll
    for (int p = 0; p < 8; ++p) {
        const int row = p * 8 + team;
        float a1 = b3k, a2 = b3k;
#pragma unroll
        for (int m = 0; m < 32; ++m) {
            a1 += us[row][m] * w3r[m];
            a2 += uq[row][m] * w3r[m];
        }
        olP[row][k] = fmaxf(a1, 0.f);
        olQ[row][k] = fmaxf(a2, 0.f);
    }
    __syncthreads();

    // matmul2: P = oP @ Wm1 + bm1 ; Q = oQ @ Wm1
#pragma unroll
    for (int p = 0; p < 8; ++p) {
        const int row = p * 8 + team;
        float a1 = bm1k, a2 = 0.f;
#pragma unroll
        for (int m = 0; m < 32; ++m) {
            a1 += olP[row][m] * wm1r[m];
            a2 += olQ[row][m] * wm1r[m];
        }
        Pl[row][k] = a1;
        Ql[row][k] = a2;
    }
    __syncthreads();

    // delta core + Shat update + new partials (R1-verified core)
    const int r = t >> 4, c = t & 15;
    float acc[4][4] = {};
#pragma unroll
    for (int q = 0; q < 8; ++q) {
        float4 w = ((const float4*)Wm2)[q];
        float4 pa[4], qb[4];
#pragma unroll
        for (int a = 0; a < 4; ++a) pa[a] = *(const float4*)&Pl[r + 16 * a][q * 4];
#pragma unroll
        for (int b = 0; b < 4; ++b) qb[b] = *(const float4*)&Ql[c + 16 * b][q * 4];
#pragma unroll
        for (int a = 0; a < 4; ++a)
#pragma unroll
            for (int b = 0; b < 4; ++b)
                acc[a][b] += w.x * fmaxf(pa[a].x - qb[b].x, 0.f)
                           + w.y * fmaxf(pa[a].y - qb[b].y, 0.f)
                           + w.z * fmaxf(pa[a].z - qb[b].z, 0.f)
                           + w.w * fmaxf(pa[a].w - qb[b].w, 0.f);
    }
#pragma unroll
    for (int a = 0; a < 4; ++a) {
        float v[4];
#pragma unroll
        for (int b = 0; b < 4; ++b) {
            size_t idx = (size_t)(i0 + r + 16 * a) * 1024 + (j0 + c + 16 * b);
            v[b] = Shat[idx] + acc[a][b] + bv;
            Shat[idx] = v[b];
        }
        float M = fmaxf(fmaxf(v[0], v[1]), fmaxf(v[2], v[3]));
#pragma unroll
        for (int m = 1; m < 16; m <<= 1) M = fmaxf(M, __shfl_xor(M, m, 16));
        float Ss = 0.f;
#pragma unroll
        for (int b = 0; b < 4; ++b) Ss += __expf(v[b] - M);
#pragma unroll
        for (int m = 1; m < 16; m <<= 1) Ss += __shfl_xor(Ss, m, 16);
        if (c == 0)
            part[(size_t)(i0 + r + 16 * a) * 16 + bx] = make_float2(M, Ss);
    }
}

// ---------------------------------------------------------------------------
// k_fsm: final softmax S_L from partials. grid 1024 x 256. (verified)
// ---------------------------------------------------------------------------
__global__ __launch_bounds__(256) void k_fsm(const float* __restrict__ Shat,
                                             const float2* __restrict__ part,
                                             float* __restrict__ out2) {
    int i = blockIdx.x, t = threadIdx.x;
    const float2* pr = part + (size_t)i * 16;
    float M = -1e30f, S = 0.f;
    float2 ps[16];
#pragma unroll
    for (int q = 0; q < 16; ++q) { ps[q] = pr[q]; M = fmaxf(M, ps[q].x); }
#pragma unroll
    for (int q = 0; q < 16; ++q) S += ps[q].y * __expf(ps[q].x - M);
    float inv = 1.f / S;
    const float* row = Shat + (size_t)i * 1024;
#pragma unroll
    for (int j = 0; j < 4; ++j)
        out2[(size_t)i * 1024 + t + 256 * j] = __expf(row[t + 256 * j] - M) * inv;
}

// ---------------------------------------------------------------------------
extern "C" void kernel_launch(void* const* d_in, const int* in_sizes, int n_in,
                              void* d_out, int out_size, void* d_ws, size_t ws_size,
                              hipStream_t stream) {
    const float* inputs = (const float*)d_in[0];
    const int*   idx1   = (const int*)d_in[1];
    const int*   idx2   = (const int*)d_in[2];
    const int*   es     = (const int*)d_in[3];
    const int*   et     = (const int*)d_in[4];
    const float* W1     = (const float*)d_in[5];
    const float* W2     = (const float*)d_in[6];
    const float* W3     = (const float*)d_in[7];
    const float* b3     = (const float*)d_in[8];
    const float* Wm1    = (const float*)d_in[9];
    const float* bm1    = (const float*)d_in[10];
    const float* Wm2    = (const float*)d_in[11];
    const float* bm2    = (const float*)d_in[12];
    const float* rs_all = (const float*)d_in[13];
    float* out = (float*)d_out;
    float* ws  = (float*)d_ws;

    // workspace layout (floats)
    float*  Shat  = ws;                       // 1,048,576
    float*  G     = Shat + (1 << 20);         // 16,384
    float2* part  = (float2*)(G + 16384);     // 32,768 floats
    float*  rt0   = G + 16384 + 32768;        // 32,768 ┐
    float*  rt1   = rt0 + 32768;              // 32,768 │ contiguous zero range
    float*  aggs0 = rt1 + 32768;              // 32,768 │ (rt0..aggt1, 196608)
    float*  aggs1 = aggs0 + 32768;            // 32,768 │
    float*  aggt0 = aggs1 + 32768;            // 32,768 │
    float*  aggt1 = aggt0 + 32768;            // 32,768 ┘

    k_pre<<<320, 256, 0, stream>>>(W1, W2, G, rt0);
    k_build<<<256, 256, 0, stream>>>(inputs, idx1, idx2, es, rs_all, G,
                                     aggs0, aggs1, Shat, part);
    for (int step = 0; step < NSTEP; ++step) {
        const float* rs   = rs_all + (size_t)step * N_S * R;
        float*       rtS  = step ? rt1 : rt0;
        float*       aggtS= step ? aggt1 : aggt0;
        const float* aggsS= step ? aggs1 : aggs0;
        k_rt<<<dim3(16, 8), 256, 0, stream>>>(Shat, part, rs, rtS,
                                              step == 0 ? out : nullptr);
        k_scat_t<<<2048, 256, 0, stream>>>(et, rtS, aggtS);
        k_delta<<<dim3(16, 16), 256, 0, stream>>>(rs, aggsS, rtS, aggtS,
                                                  W3, b3, Wm1, bm1, Wm2, bm2,
                                                  Shat, part);
    }
    k_fsm<<<1024, 256, 0, stream>>>(Shat, part, out + (1 << 20));
}

// Round 10
// 187.860 us; speedup vs baseline: 1.9100x; 1.1281x over previous
//
#include <hip/hip_runtime.h>
#include <math.h>

#define N_S   1024
#define N_T   1024
#define E_EDG 16384
#define R     32
#define NSTEP 2

// ---------------------------------------------------------------------------
// k_pre: G = W1 W1^T + W2 W2^T (blocks 0..127) ; zero rt0,rt1,aggs0,aggs1,
// aggt0,aggt1 (blocks 128..319; contiguous 196608 floats). grid 320 x 256
// ---------------------------------------------------------------------------
__global__ __launch_bounds__(256) void k_pre(const float* __restrict__ W1,
                                             const float* __restrict__ W2,
                                             float* __restrict__ G,
                                             float* __restrict__ zbuf) {
    const int t = threadIdx.x, bid = blockIdx.x;
    if (bid >= 128) {
        ((float4*)zbuf)[(bid - 128) * 256 + t] = make_float4(0.f, 0.f, 0.f, 0.f);
        return;
    }
    __shared__ float wa[512];
    __shared__ float wt[64][129];
    __shared__ float red[256];
    const int a = bid;
    for (int s = t; s < 512; s += 256)
        wa[s] = (s < 256) ? W1[a * 256 + s] : W2[a * 256 + (s - 256)];
    __syncthreads();
    float acc = 0.f;
    const int b = t & 127, h = t >> 7;
    for (int ci = 0; ci < 8; ++ci) {
        const float* Wsrc = (ci < 4) ? W1 : W2;
        const int cbase = (ci & 3) * 64;
#pragma unroll
        for (int it = 0; it < 8; ++it) {
            int s = it * 256 + t;
            int br = s >> 4, q = s & 15;
            float4 v = *(const float4*)(Wsrc + (size_t)br * 256 + cbase + q * 4);
            wt[q * 4 + 0][br] = v.x; wt[q * 4 + 1][br] = v.y;
            wt[q * 4 + 2][br] = v.z; wt[q * 4 + 3][br] = v.w;
        }
        __syncthreads();
        const float* wac = wa + ci * 64 + h * 32;
#pragma unroll
        for (int cc = 0; cc < 32; ++cc)
            acc += wac[cc] * wt[h * 32 + cc][b];
        __syncthreads();
    }
    red[t] = acc;
    __syncthreads();
    if (t < 128) G[a * 128 + t] = red[t] + red[t + 128];
}

// ---------------------------------------------------------------------------
// k_ys: Ys[i,a] = sum_d X[idx1[i],d] * G[d,a]  (R1-proven) + fused s-graph
// scatter tail (both steps). grid 1024 x 128 (high TLP: 4 blocks/CU).
// ---------------------------------------------------------------------------
__global__ __launch_bounds__(128) void k_ys(const float* __restrict__ X,
                                            const int* __restrict__ idx1,
                                            const float* __restrict__ G,
                                            const int* __restrict__ es,
                                            const float* __restrict__ rs_all,
                                            float* aggs0, float* aggs1,
                                            float* __restrict__ Ys) {
    int i = blockIdx.x;
    int a = threadIdx.x;
    __shared__ float x[128];
    int row = idx1[i];
    x[a] = X[(size_t)row * 128 + a];
    __syncthreads();
    float acc = 0.f;
#pragma unroll 8
    for (int d = 0; d < 128; ++d)
        acc += x[d] * G[d * 128 + a];
    Ys[(size_t)i * 128 + a] = acc;

    // fused s-graph scatter (both steps): 131072 threads, 1M items -> 8 each
    int gid = i * 128 + a;
    for (int v = gid; v < 2 * E_EDG * 32; v += 131072) {
        int k = v & 31, ei = v >> 5;
        int step = ei >> 14, e = ei & (E_EDG - 1);
        int src = es[e], dst = es[E_EDG + e];
        const float* rs = rs_all + (size_t)step * N_S * R;
        float* aggs = step ? aggs1 : aggs0;
        atomicAdd(&aggs[(size_t)dst * 32 + k], rs[(size_t)src * 32 + k]);
    }
}

// ---------------------------------------------------------------------------
// k_shat: Shat[i,j] = Ys[i,:] . X[idx2[j],:] (64x64 tile) + softmax partials.
// grid (16,16) x 256. (R1-proven)
// ---------------------------------------------------------------------------
__global__ __launch_bounds__(256) void k_shat(const float* __restrict__ Ys,
                                              const float* __restrict__ X,
                                              const int* __restrict__ idx2,
                                              float* __restrict__ Shat,
                                              float2* __restrict__ part) {
    __shared__ float As[64][132];
    __shared__ float Bs[64][132];
    const int i0 = blockIdx.y * 64, j0 = blockIdx.x * 64, jt = blockIdx.x;
    const int t = threadIdx.x;
    for (int s = t; s < 64 * 32; s += 256) {
        int row = s >> 5, q = s & 31;
        *(float4*)&As[row][q * 4] =
            ((const float4*)(Ys + (size_t)(i0 + row) * 128))[q];
    }
    for (int s = t; s < 64 * 32; s += 256) {
        int row = s >> 5, q = s & 31;
        int src = idx2[j0 + row];
        *(float4*)&Bs[row][q * 4] =
            ((const float4*)(X + (size_t)src * 128))[q];
    }
    __syncthreads();
    const int r = t >> 4, c = t & 15;
    float acc[4][4] = {};
    for (int k = 0; k < 128; k += 4) {
        float4 ya[4], xb[4];
#pragma unroll
        for (int a = 0; a < 4; ++a) ya[a] = *(const float4*)&As[r + 16 * a][k];
#pragma unroll
        for (int b = 0; b < 4; ++b) xb[b] = *(const float4*)&Bs[c + 16 * b][k];
#pragma unroll
        for (int a = 0; a < 4; ++a)
#pragma unroll
            for (int b = 0; b < 4; ++b)
                acc[a][b] += ya[a].x * xb[b].x + ya[a].y * xb[b].y +
                             ya[a].z * xb[b].z + ya[a].w * xb[b].w;
    }
#pragma unroll
    for (int a = 0; a < 4; ++a) {
#pragma unroll
        for (int b = 0; b < 4; ++b)
            Shat[(size_t)(i0 + r + 16 * a) * 1024 + (j0 + c + 16 * b)] = acc[a][b];
        float M = fmaxf(fmaxf(acc[a][0], acc[a][1]), fmaxf(acc[a][2], acc[a][3]));
#pragma unroll
        for (int m = 1; m < 16; m <<= 1) M = fmaxf(M, __shfl_xor(M, m, 16));
        float Ss = 0.f;
#pragma unroll
        for (int b = 0; b < 4; ++b) Ss += __expf(acc[a][b] - M);
#pragma unroll
        for (int m = 1; m < 16; m <<= 1) Ss += __shfl_xor(Ss, m, 16);
        if (c == 0)
            part[(size_t)(i0 + r + 16 * a) * 16 + jt] = make_float2(M, Ss);
    }
}

// ---------------------------------------------------------------------------
// k_rt: rt[j,k] += sum_i softmax(Shat)[i,j]*rs[i,k]; inline softmax from
// partials; step0 writes S_0 to out0. grid (16 jt, 8 ichunk) x 256. (proven)
// ---------------------------------------------------------------------------
__global__ __launch_bounds__(256) void k_rt(const float* __restrict__ Shat,
                                            const float2* __restrict__ part,
                                            const float* __restrict__ rs,
                                            float* __restrict__ rt,
                                            float* __restrict__ out0) {
    int j0 = blockIdx.x * 64;
    int i0 = blockIdx.y * 128;
    int t = threadIdx.x;
    __shared__ float Sl[16][68];
    __shared__ float Rl[16][36];
    __shared__ float mrow[128], irow[128];
    if (t < 128) {
        const float2* pr = part + (size_t)(i0 + t) * 16;
        float M = -1e30f, S = 0.f;
        float2 ps[16];
#pragma unroll
        for (int q = 0; q < 16; ++q) { ps[q] = pr[q]; M = fmaxf(M, ps[q].x); }
#pragma unroll
        for (int q = 0; q < 16; ++q) S += ps[q].y * __expf(ps[q].x - M);
        mrow[t] = M;
        irow[t] = 1.f / S;
    }
    __syncthreads();
    int k = t & 31, jg = t >> 5;
    float acc[8] = {};
    for (int ic = 0; ic < 128; ic += 16) {
        for (int s = t; s < 16 * 16; s += 256) {
            int row = s >> 4, q = s & 15;
            int lr = ic + row;
            float4 v = ((const float4*)(Shat + (size_t)(i0 + lr) * 1024 + j0))[q];
            float m = mrow[lr], inv = irow[lr];
            v.x = __expf(v.x - m) * inv;
            v.y = __expf(v.y - m) * inv;
            v.z = __expf(v.z - m) * inv;
            v.w = __expf(v.w - m) * inv;
            *(float4*)&Sl[row][q * 4] = v;
            if (out0)
                ((float4*)(out0 + (size_t)(i0 + lr) * 1024 + j0))[q] = v;
        }
        for (int s = t; s < 16 * 8; s += 256) {
            int row = s >> 3, q = s & 7;
            *(float4*)&Rl[row][q * 4] =
                ((const float4*)(rs + (size_t)(i0 + ic + row) * 32))[q];
        }
        __syncthreads();
#pragma unroll
        for (int ii = 0; ii < 16; ++ii) {
            float rv = Rl[ii][k];
#pragma unroll
            for (int m = 0; m < 8; ++m)
                acc[m] += Sl[ii][jg * 8 + m] * rv;
        }
        __syncthreads();
    }
#pragma unroll
    for (int m = 0; m < 8; ++m)
        atomicAdd(&rt[(size_t)(j0 + jg * 8 + m) * 32 + k], acc[m]);
}

// ---------------------------------------------------------------------------
// k_scat_t: aggt[dst] += rt[src].  grid 2048 x 256. (proven)
// ---------------------------------------------------------------------------
__global__ __launch_bounds__(256) void k_scat_t(const int* __restrict__ et,
                                                const float* __restrict__ rt,
                                                float* __restrict__ aggt) {
    int gid = blockIdx.x * 256 + threadIdx.x;
    int k = gid & 31;
    int e = gid >> 5;
    int src = et[e], dst = et[E_EDG + e];
    atomicAdd(&aggt[(size_t)dst * 32 + k], rt[(size_t)src * 32 + k]);
}

// ---------------------------------------------------------------------------
// k_delta: per 64x64 tile — P rows (i-side) and Q rows (j-side) computed
// in-tile with register weight columns + LDS broadcast operands. Then
// Shat += bm2 + Wm2 . relu(P-Q), emit new softmax partials. grid (16,16)x256.
// (R9-proven fast)
// ---------------------------------------------------------------------------
__global__ __launch_bounds__(256) void k_delta(
    const float* __restrict__ rs, const float* __restrict__ aggs,
    const float* __restrict__ rt, const float* __restrict__ aggt,
    const float* __restrict__ W3, const float* __restrict__ b3,
    const float* __restrict__ Wm1, const float* __restrict__ bm1,
    const float* __restrict__ Wm2, const float* __restrict__ bm2,
    float* __restrict__ Shat, float2* __restrict__ part) {
    __shared__ float us[64][33], uq[64][33];
    __shared__ float olP[64][33], olQ[64][33];
    __shared__ float Pl[64][36], Ql[64][36];
    const int t = threadIdx.x;
    const int bx = blockIdx.x, by = blockIdx.y;
    const int i0 = by * 64, j0 = bx * 64;
    const int k = t & 31, team = t >> 5;

    float w3r[32], wm1r[32];
#pragma unroll
    for (int m = 0; m < 32; ++m) {
        w3r[m]  = W3[m * 32 + k];
        wm1r[m] = Wm1[m * 32 + k];
    }
    const float b3k = b3[k], bm1k = bm1[k], bv = bm2[0];

    for (int s = t; s < 64 * 8; s += 256) {
        int row = s >> 3, q = s & 7;
        float4 a4 = ((const float4*)(rs + (size_t)(i0 + row) * 32))[q];
        float4 b4 = ((const float4*)(aggs + (size_t)(i0 + row) * 32))[q];
        a4.x += b4.x; a4.y += b4.y; a4.z += b4.z; a4.w += b4.w;
        *(float4*)&us[row][q * 4] = a4;
        float4 c4 = ((const float4*)(rt + (size_t)(j0 + row) * 32))[q];
        float4 d4 = ((const float4*)(aggt + (size_t)(j0 + row) * 32))[q];
        c4.x += d4.x; c4.y += d4.y; c4.z += d4.z; c4.w += d4.w;
        *(float4*)&uq[row][q * 4] = c4;
    }
    __syncthreads();

#pragma unroll
    for (int p = 0; p < 8; ++p) {
        const int row = p * 8 + team;
        float a1 = b3k, a2 = b3k;
#pragma unroll
        for (int m = 0; m < 32; ++m) {
            a1 += us[row][m] * w3r[m];
            a2 += uq[row][m] * w3r[m];
        }
        olP[row][k] = fmaxf(a1, 0.f);
        olQ[row][k] = fmaxf(a2, 0.f);
    }
    __syncthreads();

#pragma unroll
    for (int p = 0; p < 8; ++p) {
        const int row = p * 8 + team;
        float a1 = bm1k, a2 = 0.f;
#pragma unroll
        for (int m = 0; m < 32; ++m) {
            a1 += olP[row][m] * wm1r[m];
            a2 += olQ[row][m] * wm1r[m];
        }
        Pl[row][k] = a1;
        Ql[row][k] = a2;
    }
    __syncthreads();

    const int r = t >> 4, c = t & 15;
    float acc[4][4] = {};
#pragma unroll
    for (int q = 0; q < 8; ++q) {
        float4 w = ((const float4*)Wm2)[q];
        float4 pa[4], qb[4];
#pragma unroll
        for (int a = 0; a < 4; ++a) pa[a] = *(const float4*)&Pl[r + 16 * a][q * 4];
#pragma unroll
        for (int b = 0; b < 4; ++b) qb[b] = *(const float4*)&Ql[c + 16 * b][q * 4];
#pragma unroll
        for (int a = 0; a < 4; ++a)
#pragma unroll
            for (int b = 0; b < 4; ++b)
                acc[a][b] += w.x * fmaxf(pa[a].x - qb[b].x, 0.f)
                           + w.y * fmaxf(pa[a].y - qb[b].y, 0.f)
                           + w.z * fmaxf(pa[a].z - qb[b].z, 0.f)
                           + w.w * fmaxf(pa[a].w - qb[b].w, 0.f);
    }
#pragma unroll
    for (int a = 0; a < 4; ++a) {
        float v[4];
#pragma unroll
        for (int b = 0; b < 4; ++b) {
            size_t idx = (size_t)(i0 + r + 16 * a) * 1024 + (j0 + c + 16 * b);
            v[b] = Shat[idx] + acc[a][b] + bv;
            Shat[idx] = v[b];
        }
        float M = fmaxf(fmaxf(v[0], v[1]), fmaxf(v[2], v[3]));
#pragma unroll
        for (int m = 1; m < 16; m <<= 1) M = fmaxf(M, __shfl_xor(M, m, 16));
        float Ss = 0.f;
#pragma unroll
        for (int b = 0; b < 4; ++b) Ss += __expf(v[b] - M);
#pragma unroll
        for (int m = 1; m < 16; m <<= 1) Ss += __shfl_xor(Ss, m, 16);
        if (c == 0)
            part[(size_t)(i0 + r + 16 * a) * 16 + bx] = make_float2(M, Ss);
    }
}

// ---------------------------------------------------------------------------
// k_fsm: final softmax S_L from partials. grid 1024 x 256. (proven)
// ---------------------------------------------------------------------------
__global__ __launch_bounds__(256) void k_fsm(const float* __restrict__ Shat,
                                             const float2* __restrict__ part,
                                             float* __restrict__ out2) {
    int i = blockIdx.x, t = threadIdx.x;
    const float2* pr = part + (size_t)i * 16;
    float M = -1e30f, S = 0.f;
    float2 ps[16];
#pragma unroll
    for (int q = 0; q < 16; ++q) { ps[q] = pr[q]; M = fmaxf(M, ps[q].x); }
#pragma unroll
    for (int q = 0; q < 16; ++q) S += ps[q].y * __expf(ps[q].x - M);
    float inv = 1.f / S;
    const float* row = Shat + (size_t)i * 1024;
#pragma unroll
    for (int j = 0; j < 4; ++j)
        out2[(size_t)i * 1024 + t + 256 * j] = __expf(row[t + 256 * j] - M) * inv;
}

// ---------------------------------------------------------------------------
extern "C" void kernel_launch(void* const* d_in, const int* in_sizes, int n_in,
                              void* d_out, int out_size, void* d_ws, size_t ws_size,
                              hipStream_t stream) {
    const float* inputs = (const float*)d_in[0];
    const int*   idx1   = (const int*)d_in[1];
    const int*   idx2   = (const int*)d_in[2];
    const int*   es     = (const int*)d_in[3];
    const int*   et     = (const int*)d_in[4];
    const float* W1     = (const float*)d_in[5];
    const float* W2     = (const float*)d_in[6];
    const float* W3     = (const float*)d_in[7];
    const float* b3     = (const float*)d_in[8];
    const float* Wm1    = (const float*)d_in[9];
    const float* bm1    = (const float*)d_in[10];
    const float* Wm2    = (const float*)d_in[11];
    const float* bm2    = (const float*)d_in[12];
    const float* rs_all = (const float*)d_in[13];
    float* out = (float*)d_out;
    float* ws  = (float*)d_ws;

    // workspace layout (floats)
    float*  Shat  = ws;                       // 1,048,576
    float*  Ys    = Shat + (1 << 20);         // 131,072
    float*  G     = Ys + 131072;              // 16,384
    float2* part  = (float2*)(G + 16384);     // 32,768 floats
    float*  rt0   = G + 16384 + 32768;        // 32,768 ┐
    float*  rt1   = rt0 + 32768;              // 32,768 │ contiguous zero range
    float*  aggs0 = rt1 + 32768;              // 32,768 │ (rt0..aggt1, 196608)
    float*  aggs1 = aggs0 + 32768;            // 32,768 │
    float*  aggt0 = aggs1 + 32768;            // 32,768 │
    float*  aggt1 = aggt0 + 32768;            // 32,768 ┘

    k_pre<<<320, 256, 0, stream>>>(W1, W2, G, rt0);
    k_ys<<<1024, 128, 0, stream>>>(inputs, idx1, G, es, rs_all,
                                   aggs0, aggs1, Ys);
    k_shat<<<dim3(16, 16), 256, 0, stream>>>(Ys, inputs, idx2, Shat, part);
    for (int step = 0; step < NSTEP; ++step) {
        const float* rs    = rs_all + (size_t)step * N_S * R;
        float*       rtS   = step ? rt1 : rt0;
        float*       aggtS = step ? aggt1 : aggt0;
        const float* aggsS = step ? aggs1 : aggs0;
        k_rt<<<dim3(16, 8), 256, 0, stream>>>(Shat, part, rs, rtS,
                                              step == 0 ? out : nullptr);
        k_scat_t<<<2048, 256, 0, stream>>>(et, rtS, aggtS);
        k_delta<<<dim3(16, 16), 256, 0, stream>>>(rs, aggsS, rtS, aggtS,
                                                  W3, b3, Wm1, bm1, Wm2, bm2,
                                                  Shat, part);
    }
    k_fsm<<<1024, 256, 0, stream>>>(Shat, part, out + (1 << 20));
}